// Round 3
// baseline (1861.833 us; speedup 1.0000x reference)
//
#include <hip/hip_runtime.h>

#define N_ATOMS 100000
#define N_PAIRS 1600000
#define F_A 75
#define F_P 14
#define H 50

typedef float f32x2 __attribute__((ext_vector_type(2)));
typedef float f32x4 __attribute__((ext_vector_type(4)));
typedef short bf16x8 __attribute__((ext_vector_type(8)));

__device__ inline unsigned short f2bf(float f) {
    unsigned u = __float_as_uint(f);
    u += 0x7fffu + ((u >> 16) & 1u);
    return (unsigned short)(u >> 16);
}
__device__ inline float bfu(unsigned u, int hi) {
    return __uint_as_float(hi ? (u & 0xffff0000u) : (u << 16));
}

// ---------------- kernel 0: row_start[a] = lower_bound(split, a) ----------------
__global__ __launch_bounds__(256) void k_row_starts(
    const int* __restrict__ split, int* __restrict__ row_start)
{
    int p = blockIdx.x * 256 + threadIdx.x;
    if (p >= N_PAIRS) return;
    int s = split[p];
    int sp = (p == 0) ? -1 : split[p - 1];
    for (int a = sp + 1; a <= s; ++a) row_start[a] = p;
    if (p == N_PAIRS - 1)
        for (int a = s + 1; a <= N_ATOMS; ++a) row_start[a] = N_PAIRS;
}

// ---------------- kernel 1: atom projections AA (f32), X (packed bf16) ----------------
// X row = 128 bf16 (256B aligned): [0..49]=X1+b_AP, [50..63]=0, [64..113]=X2, [114..127]=0
__global__ __launch_bounds__(256) void k_atom_proj(
    const float* __restrict__ af, const float* __restrict__ W_AA,
    const float* __restrict__ b_AA, const float* __restrict__ W_AP,
    const float* __restrict__ b_AP,
    float* __restrict__ AA, unsigned short* __restrict__ X)
{
    __shared__ float sWAA[F_A * H];
    __shared__ float sWAP[2 * F_A * H];
    __shared__ float sbAA[H];
    __shared__ float sbAP[64];
    for (int t = threadIdx.x; t < F_A * H; t += 256) sWAA[t] = W_AA[t];
    for (int t = threadIdx.x; t < 2 * F_A * H; t += 256) sWAP[t] = W_AP[t];
    if (threadIdx.x < H) sbAA[threadIdx.x] = b_AA[threadIdx.x];
    if (threadIdx.x < 64) sbAP[threadIdx.x] = threadIdx.x < H ? b_AP[threadIdx.x] : 0.f;
    __syncthreads();

    const int wave = __builtin_amdgcn_readfirstlane(threadIdx.x >> 6);
    const int lane = threadIdx.x & 63;
    const int h = lane < H ? lane : 0;
    const int base = blockIdx.x * 32 + wave * 8;

    float aa[8], x1[8], x2[8];
    #pragma unroll
    for (int a = 0; a < 8; ++a) { aa[a] = sbAA[h]; x1[a] = 0.f; x2[a] = 0.f; }

    for (int c = 0; c < F_A; ++c) {
        float waa = sWAA[c * H + h];
        float w1  = sWAP[c * H + h];
        float w2  = sWAP[(F_A + c) * H + h];
        #pragma unroll
        for (int a = 0; a < 8; ++a) {
            float f = af[(base + a) * F_A + c];
            aa[a] = fmaf(f, waa, aa[a]);
            x1[a] = fmaf(f, w1, x1[a]);
            x2[a] = fmaf(f, w2, x2[a]);
        }
    }
    #pragma unroll
    for (int a = 0; a < 8; ++a) {
        int atom = base + a;
        if (lane < H) AA[(size_t)atom * H + lane] = fmaxf(aa[a], 0.f);
        unsigned short v1 = (lane < H) ? f2bf(x1[a] + sbAP[lane]) : (unsigned short)0;
        unsigned short v2 = (lane < H) ? f2bf(x2[a]) : (unsigned short)0;
        unsigned short* Xrow = X + (size_t)atom * 128;
        Xrow[lane]      = v1;
        Xrow[64 + lane] = v2;
    }
}

// ---------------- kernel 2: PA = segment_sum(relu(pf@W_PA+b)) ----------------
__global__ __launch_bounds__(256) void k_pa_segsum(
    const float* __restrict__ pf, const int* __restrict__ row_start,
    const float* __restrict__ W_PA, const float* __restrict__ b_PA,
    float* __restrict__ PA)
{
    const int wave = __builtin_amdgcn_readfirstlane(threadIdx.x >> 6);
    const int lane = threadIdx.x & 63;
    const int h = lane < H ? lane : 0;
    const int atom = blockIdx.x * 4 + wave;

    float w[F_P];
    #pragma unroll
    for (int c = 0; c < F_P; ++c) w[c] = W_PA[c * H + h];
    const float bias = b_PA[h];

    const int start = row_start[atom];
    const int end   = row_start[atom + 1];

    float acc = 0.f;
    int p = start;
    for (; p + 2 <= end; p += 2) {
        const f32x2* r0 = (const f32x2*)(pf + (size_t)p * F_P);
        const f32x2* r1 = (const f32x2*)(pf + (size_t)(p + 1) * F_P);
        float s0 = bias, s1 = bias;
        #pragma unroll
        for (int c = 0; c < 7; ++c) {
            f32x2 v0 = r0[c], v1 = r1[c];
            s0 = fmaf(v0.x, w[2*c], s0); s0 = fmaf(v0.y, w[2*c+1], s0);
            s1 = fmaf(v1.x, w[2*c], s1); s1 = fmaf(v1.y, w[2*c+1], s1);
        }
        acc += fmaxf(s0, 0.f) + fmaxf(s1, 0.f);
    }
    if (p < end) {
        const f32x2* r0 = (const f32x2*)(pf + (size_t)p * F_P);
        float s0 = bias;
        #pragma unroll
        for (int c = 0; c < 7; ++c) {
            f32x2 v = r0[c];
            s0 = fmaf(v.x, w[2*c], s0); s0 = fmaf(v.y, w[2*c+1], s0);
        }
        acc += fmaxf(s0, 0.f);
    }
    if (lane < H) PA[(size_t)atom * H + lane] = acc;
}

// ---------------- kernel 3: A = relu([AA|PA] @ W_A + b_A) ----------------
__global__ __launch_bounds__(256) void k_atom_out(
    const float* __restrict__ AA, const float* __restrict__ PA,
    const float* __restrict__ W_A, const float* __restrict__ b_A,
    float* __restrict__ outA)
{
    __shared__ float sW[2 * H * H];
    __shared__ float sb[H];
    for (int t = threadIdx.x; t < 2 * H * H; t += 256) sW[t] = W_A[t];
    if (threadIdx.x < H) sb[threadIdx.x] = b_A[threadIdx.x];
    __syncthreads();

    const int wave = __builtin_amdgcn_readfirstlane(threadIdx.x >> 6);
    const int lane = threadIdx.x & 63;
    const int h = lane < H ? lane : 0;
    const int base = blockIdx.x * 32 + wave * 8;

    float acc[8];
    #pragma unroll
    for (int a = 0; a < 8; ++a) acc[a] = sb[h];

    for (int k = 0; k < H; ++k) {
        float wA = sW[k * H + h];
        float wP = sW[(H + k) * H + h];
        #pragma unroll
        for (int a = 0; a < 8; ++a) {
            acc[a] = fmaf(AA[(size_t)(base + a) * H + k], wA, acc[a]);
            acc[a] = fmaf(PA[(size_t)(base + a) * H + k], wP, acc[a]);
        }
    }
    #pragma unroll
    for (int a = 0; a < 8; ++a)
        if (lane < H) outA[(size_t)(base + a) * H + lane] = fmaxf(acc[a], 0.f);
}

// ---------------- kernel 4: P = relu([AP|PP] @ W_P + b_P) via MFMA ----------------
// Wave = 16 pairs/tile, 4 tiles. A (16x128 bf16): K 0..63 = AP (built from X gathers),
// K 64..127 = PP (computed in-lane from pf @ W_PP). B = W_P padded [128][64] bf16 frags in LDS.
__global__ __launch_bounds__(256, 3) void k_pair_out(
    const float* __restrict__ pf, const int* __restrict__ a2p,
    const unsigned short* __restrict__ X,
    const float* __restrict__ W_PP, const float* __restrict__ b_PP,
    const float* __restrict__ W_P, const float* __restrict__ b_P,
    float* __restrict__ outP)
{
    __shared__ uint4 sWf[1024];        // 16 B-frag sets (s=0..3, n=0..3) x 64 lanes
    __shared__ float sWPP[F_P][64];    // W_PP transposed-free, o-padded to 64
    __shared__ float sbPP[64];

    const int tid = threadIdx.x;
    // build B-frags: lane holds col=lane&15, k = s*32 + (lane>>4)*8 + [0..7]
    #pragma unroll
    for (int r = 0; r < 4; ++r) {
        int e = r * 256 + tid;
        int fid = e >> 6, lane_e = e & 63;
        int s_ = fid >> 2, n_ = fid & 3;
        int col = lane_e & 15, gg = lane_e >> 4;
        int k0 = s_ * 32 + gg * 8;
        int c = n_ * 16 + col;
        unsigned w[4];
        #pragma unroll
        for (int hh = 0; hh < 4; ++hh) {
            float vlo = 0.f, vhi = 0.f;
            if (c < H) {
                int k = k0 + 2 * hh;
                int r0 = (k < 64) ? (k < H ? k : -1) : ((k - 64) < H ? H + (k - 64) : -1);
                int k2 = k + 1;
                int r1 = (k2 < 64) ? (k2 < H ? k2 : -1) : ((k2 - 64) < H ? H + (k2 - 64) : -1);
                if (r0 >= 0) vlo = W_P[r0 * H + c];
                if (r1 >= 0) vhi = W_P[r1 * H + c];
            }
            w[hh] = (unsigned)f2bf(vlo) | ((unsigned)f2bf(vhi) << 16);
        }
        sWf[e] = make_uint4(w[0], w[1], w[2], w[3]);
    }
    for (int t = tid; t < F_P * 64; t += 256) {
        int c = t >> 6, o = t & 63;
        sWPP[c][o] = (o < H) ? W_PP[c * H + o] : 0.f;
    }
    if (tid < 64) sbPP[tid] = tid < H ? b_PP[tid] : 0.f;
    __syncthreads();

    const int lane = tid & 63;
    const int wave = tid >> 6;
    const int col = lane & 15;          // pair-local index AND output col-local
    const int g = lane >> 4;            // k-slice group
    const int wavebase = blockIdx.x * 256 + wave * 64;

    float bP[4];
    #pragma unroll
    for (int n = 0; n < 4; ++n) {
        int c = n * 16 + col;
        bP[n] = (c < H) ? b_P[c] : 0.f;
    }

    // prefetch pair indices for all 4 tiles
    int2 ij[4];
    #pragma unroll
    for (int t = 0; t < 4; ++t)
        ij[t] = ((const int2*)a2p)[wavebase + t * 16 + col];

    for (int t = 0; t < 4; ++t) {
        const int pairbase = wavebase + t * 16;
        const unsigned short* Xi = X + (size_t)ij[t].x * 128;
        const unsigned short* Xj = X + (size_t)ij[t].y * 128;

        // issue all 8 gathers early (each 16B, lane owns its frag chunk)
        uint4 A1[2], B2[2], B1[2], A2[2];
        #pragma unroll
        for (int s = 0; s < 2; ++s) {
            int off = s * 32 + g * 8;   // ushort offset
            A1[s] = *(const uint4*)(Xi + off);
            B2[s] = *(const uint4*)(Xj + 64 + off);
            B1[s] = *(const uint4*)(Xj + off);
            A2[s] = *(const uint4*)(Xi + 64 + off);
        }

        // pf row for PP (pair = col)
        float pfr[F_P];
        {
            const f32x2* src = (const f32x2*)(pf + (size_t)(pairbase + col) * F_P);
            #pragma unroll
            for (int c = 0; c < 7; ++c) { f32x2 v = src[c]; pfr[2*c] = v.x; pfr[2*c+1] = v.y; }
        }

        f32x4 acc[4];
        #pragma unroll
        for (int n = 0; n < 4; ++n) acc[n] = (f32x4){bP[n], bP[n], bP[n], bP[n]};

        // ---- PP K-steps (global k = 64..127): overlap with gather latency ----
        #pragma unroll
        for (int s2 = 0; s2 < 2; ++s2) {
            int ob = s2 * 32 + g * 8;
            float pp[8];
            {
                const f32x4* bb = (const f32x4*)&sbPP[ob];
                f32x4 b0 = bb[0], b1 = bb[1];
                pp[0]=b0.x; pp[1]=b0.y; pp[2]=b0.z; pp[3]=b0.w;
                pp[4]=b1.x; pp[5]=b1.y; pp[6]=b1.z; pp[7]=b1.w;
            }
            #pragma unroll
            for (int c = 0; c < F_P; ++c) {
                const f32x4* wr = (const f32x4*)&sWPP[c][ob];
                f32x4 w0 = wr[0], w1 = wr[1];
                float pc = pfr[c];
                pp[0]=fmaf(pc,w0.x,pp[0]); pp[1]=fmaf(pc,w0.y,pp[1]);
                pp[2]=fmaf(pc,w0.z,pp[2]); pp[3]=fmaf(pc,w0.w,pp[3]);
                pp[4]=fmaf(pc,w1.x,pp[4]); pp[5]=fmaf(pc,w1.y,pp[5]);
                pp[6]=fmaf(pc,w1.z,pp[6]); pp[7]=fmaf(pc,w1.w,pp[7]);
            }
            union { unsigned u[4]; bf16x8 v; } ap;
            #pragma unroll
            for (int hh = 0; hh < 4; ++hh) {
                float lo = fmaxf(pp[2*hh], 0.f), hi = fmaxf(pp[2*hh+1], 0.f);
                ap.u[hh] = (unsigned)f2bf(lo) | ((unsigned)f2bf(hi) << 16);
            }
            int sg = 2 + s2;
            #pragma unroll
            for (int n = 0; n < 4; ++n) {
                bf16x8 bfr = ((const bf16x8*)sWf)[(sg * 4 + n) * 64 + lane];
                acc[n] = __builtin_amdgcn_mfma_f32_16x16x32_bf16(ap.v, bfr, acc[n], 0, 0, 0);
            }
        }

        // ---- AP K-steps (global k = 0..63) ----
        #pragma unroll
        for (int s = 0; s < 2; ++s) {
            const unsigned* a1 = (const unsigned*)&A1[s];
            const unsigned* b2 = (const unsigned*)&B2[s];
            const unsigned* b1 = (const unsigned*)&B1[s];
            const unsigned* a2 = (const unsigned*)&A2[s];
            union { unsigned u[4]; bf16x8 v; } ap;
            #pragma unroll
            for (int hh = 0; hh < 4; ++hh) {
                float e1l = bfu(a1[hh],0) + bfu(b2[hh],0);
                float e2l = bfu(b1[hh],0) + bfu(a2[hh],0);
                float apl = fmaxf(e1l, 0.f) + fmaxf(e2l, 0.f);
                float e1h = bfu(a1[hh],1) + bfu(b2[hh],1);
                float e2h = bfu(b1[hh],1) + bfu(a2[hh],1);
                float aph = fmaxf(e1h, 0.f) + fmaxf(e2h, 0.f);
                ap.u[hh] = (unsigned)f2bf(apl) | ((unsigned)f2bf(aph) << 16);
            }
            #pragma unroll
            for (int n = 0; n < 4; ++n) {
                bf16x8 bfr = ((const bf16x8*)sWf)[(s * 4 + n) * 64 + lane];
                acc[n] = __builtin_amdgcn_mfma_f32_16x16x32_bf16(ap.v, bfr, acc[n], 0, 0, 0);
            }
        }

        // ---- epilogue: C frag (col=lane&15, row=(lane>>4)*4+q), relu, store ----
        #pragma unroll
        for (int n = 0; n < 4; ++n) {
            int c = n * 16 + col;
            if (c < H) {
                #pragma unroll
                for (int q = 0; q < 4; ++q)
                    outP[(size_t)(pairbase + g * 4 + q) * H + c] = fmaxf(acc[n][q], 0.f);
            }
        }
    }
}

// ---------------- launcher ----------------
extern "C" void kernel_launch(void* const* d_in, const int* in_sizes, int n_in,
                              void* d_out, int out_size, void* d_ws, size_t ws_size,
                              hipStream_t stream) {
    const float* af    = (const float*)d_in[0];
    const float* pfeat = (const float*)d_in[1];
    const int*   split = (const int*)d_in[2];
    const int*   a2p   = (const int*)d_in[3];
    const float* W_AA  = (const float*)d_in[4];
    const float* b_AA  = (const float*)d_in[5];
    const float* W_PA  = (const float*)d_in[6];
    const float* b_PA  = (const float*)d_in[7];
    const float* W_A   = (const float*)d_in[8];
    const float* b_A   = (const float*)d_in[9];
    const float* W_AP  = (const float*)d_in[10];
    const float* b_AP  = (const float*)d_in[11];
    const float* W_PP  = (const float*)d_in[12];
    const float* b_PP  = (const float*)d_in[13];
    const float* W_P   = (const float*)d_in[14];
    const float* b_P   = (const float*)d_in[15];

    float* outA = (float*)d_out;
    float* outP = (float*)d_out + (size_t)N_ATOMS * H;

    unsigned short* X  = (unsigned short*)d_ws;              // 100000*128*2B = 25.6MB
    float* AA          = (float*)(X + (size_t)N_ATOMS * 128);// 20MB
    float* PA          = AA + (size_t)N_ATOMS * H;           // 20MB
    int*   row_start   = (int*)(PA + (size_t)N_ATOMS * H);   // (N_ATOMS+1)*4B

    k_row_starts<<<(N_PAIRS + 255) / 256, 256, 0, stream>>>(split, row_start);
    k_atom_proj<<<N_ATOMS / 32, 256, 0, stream>>>(af, W_AA, b_AA, W_AP, b_AP, AA, X);
    k_pa_segsum<<<N_ATOMS / 4, 256, 0, stream>>>(pfeat, row_start, W_PA, b_PA, PA);
    k_atom_out<<<N_ATOMS / 32, 256, 0, stream>>>(AA, PA, W_A, b_A, outA);
    k_pair_out<<<N_PAIRS / 256, 256, 0, stream>>>(pfeat, a2p, X,
                                                  W_PP, b_PP, W_P, b_P, outP);
}

// Round 4
// 1163.608 us; speedup vs baseline: 1.6001x; 1.6001x over previous
//
#include <hip/hip_runtime.h>

#define N_ATOMS 100000
#define N_PAIRS 1600000
#define F_A 75
#define F_P 14
#define H 50

typedef float f32x2 __attribute__((ext_vector_type(2)));

__device__ inline unsigned short f2bf(float f) {
    unsigned u = __float_as_uint(f);
    u += 0x7fffu + ((u >> 16) & 1u);
    return (unsigned short)(u >> 16);
}
__device__ inline float bfu(unsigned u, int hi) {
    return __uint_as_float(hi ? (u & 0xffff0000u) : (u << 16));
}

// ---------------- kernel 0: row_start[a] = lower_bound(split, a) ----------------
__global__ __launch_bounds__(256) void k_row_starts(
    const int* __restrict__ split, int* __restrict__ row_start)
{
    int p = blockIdx.x * 256 + threadIdx.x;
    if (p >= N_PAIRS) return;
    int s = split[p];
    int sp = (p == 0) ? -1 : split[p - 1];
    for (int a = sp + 1; a <= s; ++a) row_start[a] = p;
    if (p == N_PAIRS - 1)
        for (int a = s + 1; a <= N_ATOMS; ++a) row_start[a] = N_PAIRS;
}

// ---------------- kernel 1: atom projections AA (f32), X (packed bf16) ----------------
// X row layout (128 bf16 = 256B aligned): [0..49]=X1+b_AP, [50..63]=0, [64..113]=X2, [114..127]=0
__global__ __launch_bounds__(256) void k_atom_proj(
    const float* __restrict__ af, const float* __restrict__ W_AA,
    const float* __restrict__ b_AA, const float* __restrict__ W_AP,
    const float* __restrict__ b_AP,
    float* __restrict__ AA, unsigned short* __restrict__ X)
{
    __shared__ float sWAA[F_A * H];
    __shared__ float sWAP[2 * F_A * H];
    __shared__ float sbAA[H];
    __shared__ float sbAP[64];
    for (int t = threadIdx.x; t < F_A * H; t += 256) sWAA[t] = W_AA[t];
    for (int t = threadIdx.x; t < 2 * F_A * H; t += 256) sWAP[t] = W_AP[t];
    if (threadIdx.x < H) sbAA[threadIdx.x] = b_AA[threadIdx.x];
    if (threadIdx.x < 64) sbAP[threadIdx.x] = threadIdx.x < H ? b_AP[threadIdx.x] : 0.f;
    __syncthreads();

    const int wave = __builtin_amdgcn_readfirstlane(threadIdx.x >> 6);
    const int lane = threadIdx.x & 63;
    const int h = lane < H ? lane : 0;
    const int base = blockIdx.x * 32 + wave * 8;

    float aa[8], x1[8], x2[8];
    #pragma unroll
    for (int a = 0; a < 8; ++a) { aa[a] = sbAA[h]; x1[a] = 0.f; x2[a] = 0.f; }

    for (int c = 0; c < F_A; ++c) {
        float waa = sWAA[c * H + h];
        float w1  = sWAP[c * H + h];
        float w2  = sWAP[(F_A + c) * H + h];
        #pragma unroll
        for (int a = 0; a < 8; ++a) {
            float f = af[(base + a) * F_A + c];
            aa[a] = fmaf(f, waa, aa[a]);
            x1[a] = fmaf(f, w1, x1[a]);
            x2[a] = fmaf(f, w2, x2[a]);
        }
    }
    #pragma unroll
    for (int a = 0; a < 8; ++a) {
        int atom = base + a;
        if (lane < H) AA[(size_t)atom * H + lane] = fmaxf(aa[a], 0.f);
        unsigned short v1 = (lane < H) ? f2bf(x1[a] + sbAP[lane]) : (unsigned short)0;
        unsigned short v2 = (lane < H) ? f2bf(x2[a]) : (unsigned short)0;
        unsigned short* Xrow = X + (size_t)atom * 128;
        Xrow[lane]      = v1;
        Xrow[64 + lane] = v2;
    }
}

// ---------------- kernel 2: PA = segment_sum(relu(pf@W_PA+b)) ----------------
__global__ __launch_bounds__(256) void k_pa_segsum(
    const float* __restrict__ pf, const int* __restrict__ row_start,
    const float* __restrict__ W_PA, const float* __restrict__ b_PA,
    float* __restrict__ PA)
{
    const int wave = __builtin_amdgcn_readfirstlane(threadIdx.x >> 6);
    const int lane = threadIdx.x & 63;
    const int h = lane < H ? lane : 0;
    const int atom = blockIdx.x * 4 + wave;

    float w[F_P];
    #pragma unroll
    for (int c = 0; c < F_P; ++c) w[c] = W_PA[c * H + h];
    const float bias = b_PA[h];

    const int start = row_start[atom];
    const int end   = row_start[atom + 1];

    float acc = 0.f;
    int p = start;
    for (; p + 2 <= end; p += 2) {
        const f32x2* r0 = (const f32x2*)(pf + (size_t)p * F_P);
        const f32x2* r1 = (const f32x2*)(pf + (size_t)(p + 1) * F_P);
        float s0 = bias, s1 = bias;
        #pragma unroll
        for (int c = 0; c < 7; ++c) {
            f32x2 v0 = __builtin_nontemporal_load(r0 + c);
            f32x2 v1 = __builtin_nontemporal_load(r1 + c);
            s0 = fmaf(v0.x, w[2*c], s0); s0 = fmaf(v0.y, w[2*c+1], s0);
            s1 = fmaf(v1.x, w[2*c], s1); s1 = fmaf(v1.y, w[2*c+1], s1);
        }
        acc += fmaxf(s0, 0.f) + fmaxf(s1, 0.f);
    }
    if (p < end) {
        const f32x2* r0 = (const f32x2*)(pf + (size_t)p * F_P);
        float s0 = bias;
        #pragma unroll
        for (int c = 0; c < 7; ++c) {
            f32x2 v = __builtin_nontemporal_load(r0 + c);
            s0 = fmaf(v.x, w[2*c], s0); s0 = fmaf(v.y, w[2*c+1], s0);
        }
        acc += fmaxf(s0, 0.f);
    }
    if (lane < H) PA[(size_t)atom * H + lane] = acc;
}

// ---------------- kernel 3: A = relu([AA|PA] @ W_A + b_A) ----------------
__global__ __launch_bounds__(256) void k_atom_out(
    const float* __restrict__ AA, const float* __restrict__ PA,
    const float* __restrict__ W_A, const float* __restrict__ b_A,
    float* __restrict__ outA)
{
    __shared__ float sW[2 * H * H];
    __shared__ float sb[H];
    for (int t = threadIdx.x; t < 2 * H * H; t += 256) sW[t] = W_A[t];
    if (threadIdx.x < H) sb[threadIdx.x] = b_A[threadIdx.x];
    __syncthreads();

    const int wave = __builtin_amdgcn_readfirstlane(threadIdx.x >> 6);
    const int lane = threadIdx.x & 63;
    const int h = lane < H ? lane : 0;
    const int base = blockIdx.x * 32 + wave * 8;

    float acc[8];
    #pragma unroll
    for (int a = 0; a < 8; ++a) acc[a] = sb[h];

    for (int k = 0; k < H; ++k) {
        float wA = sW[k * H + h];
        float wP = sW[(H + k) * H + h];
        #pragma unroll
        for (int a = 0; a < 8; ++a) {
            acc[a] = fmaf(AA[(size_t)(base + a) * H + k], wA, acc[a]);
            acc[a] = fmaf(PA[(size_t)(base + a) * H + k], wP, acc[a]);
        }
    }
    #pragma unroll
    for (int a = 0; a < 8; ++a)
        if (lane < H) outA[(size_t)(base + a) * H + lane] = fmaxf(acc[a], 0.f);
}

// ---------------- kernel 4: P = relu([AP|PP] @ W_P + b_P) ----------------
// one pair per thread. AP reconstructed from gathered bf16 X rows (2 lines/row).
__global__ __launch_bounds__(256) void k_pair_out(
    const float* __restrict__ pf, const int* __restrict__ a2p,
    const unsigned short* __restrict__ X,
    const float* __restrict__ b_AP, const float* __restrict__ W_PP,
    const float* __restrict__ b_PP, const float* __restrict__ W_P,
    const float* __restrict__ b_P, float* __restrict__ outP)
{
    __shared__ float sWpA[56][52];   // W_P rows 0..49 (AP part), zero-padded k>=50
    __shared__ float sWpP[H][52];    // W_P rows 50..99 (PP part)
    __shared__ float sWPP[F_P][52];
    __shared__ float sbAP[64], sbPP[64], sbP[64];

    for (int t = threadIdx.x; t < 56 * 52; t += 256) {
        int k = t / 52, hh = t % 52;
        sWpA[k][hh] = (k < H && hh < H) ? W_P[k * H + hh] : 0.f;
    }
    for (int t = threadIdx.x; t < H * 52; t += 256) {
        int k = t / 52, hh = t % 52;
        sWpP[k][hh] = (hh < H) ? W_P[(H + k) * H + hh] : 0.f;
    }
    for (int t = threadIdx.x; t < F_P * 52; t += 256) {
        int c = t / 52, hh = t % 52;
        sWPP[c][hh] = (hh < H) ? W_PP[c * H + hh] : 0.f;
    }
    if (threadIdx.x < 64) {
        sbAP[threadIdx.x] = threadIdx.x < H ? b_AP[threadIdx.x] : 0.f;   // NOTE: b_AP already folded into X1; keep zeros here
        sbPP[threadIdx.x] = threadIdx.x < H ? b_PP[threadIdx.x] : 0.f;
        sbP[threadIdx.x]  = threadIdx.x < H ? b_P[threadIdx.x]  : 0.f;
    }
    __syncthreads();

    const int p = blockIdx.x * 256 + threadIdx.x;
    const int2 ij = ((const int2*)a2p)[p];
    const uint4* rowi = (const uint4*)(X + (size_t)ij.x * 128);
    const uint4* rowj = (const uint4*)(X + (size_t)ij.y * 128);

    float acc[H];
    #pragma unroll
    for (int hh = 0; hh < H; ++hh) acc[hh] = sbP[hh];

    // ---- PP part first (independent of gathers; gives loads time to land) ----
    float pfr[F_P];
    {
        const f32x2* src = (const f32x2*)(pf + (size_t)p * F_P);
        #pragma unroll
        for (int c = 0; c < 7; ++c) {
            f32x2 v = __builtin_nontemporal_load(src + c);
            pfr[2*c] = v.x; pfr[2*c+1] = v.y;
        }
    }
    for (int h2 = 0; h2 < H; ++h2) {
        float v = sbPP[h2];
        #pragma unroll
        for (int c = 0; c < F_P; ++c) v = fmaf(pfr[c], sWPP[c][h2], v);
        v = fmaxf(v, 0.f);
        #pragma unroll
        for (int hh = 0; hh < H; ++hh) acc[hh] = fmaf(v, sWpP[h2][hh], acc[hh]);
    }

    // ---- AP part: 7 chunks of 8 k-values, bf16 gathers (b_AP pre-folded into X1) ----
    #pragma unroll 2
    for (int c = 0; c < 7; ++c) {
        uint4 x1i = rowi[c], x2i = rowi[8 + c];
        uint4 x1j = rowj[c], x2j = rowj[8 + c];
        const unsigned* a1 = (const unsigned*)&x1i;
        const unsigned* a2 = (const unsigned*)&x2i;
        const unsigned* b1 = (const unsigned*)&x1j;
        const unsigned* b2 = (const unsigned*)&x2j;
        #pragma unroll
        for (int t = 0; t < 8; ++t) {
            int k = c * 8 + t;
            float e1 = bfu(a1[t >> 1], t & 1) + bfu(b2[t >> 1], t & 1);
            float e2 = bfu(b1[t >> 1], t & 1) + bfu(a2[t >> 1], t & 1);
            float ap = fmaxf(e1, 0.f) + fmaxf(e2, 0.f);
            #pragma unroll
            for (int hh = 0; hh < H; ++hh) acc[hh] = fmaf(ap, sWpA[k][hh], acc[hh]);
        }
    }

    // ---- plain, fully-covering row store (L2 merges full sectors) ----
    float* dst = outP + (size_t)p * H;
    #pragma unroll
    for (int hh = 0; hh < H; hh += 2) {
        f32x2 v; v.x = fmaxf(acc[hh], 0.f); v.y = fmaxf(acc[hh + 1], 0.f);
        *(f32x2*)(dst + hh) = v;
    }
}

// ---------------- launcher ----------------
extern "C" void kernel_launch(void* const* d_in, const int* in_sizes, int n_in,
                              void* d_out, int out_size, void* d_ws, size_t ws_size,
                              hipStream_t stream) {
    const float* af    = (const float*)d_in[0];
    const float* pfeat = (const float*)d_in[1];
    const int*   split = (const int*)d_in[2];
    const int*   a2p   = (const int*)d_in[3];
    const float* W_AA  = (const float*)d_in[4];
    const float* b_AA  = (const float*)d_in[5];
    const float* W_PA  = (const float*)d_in[6];
    const float* b_PA  = (const float*)d_in[7];
    const float* W_A   = (const float*)d_in[8];
    const float* b_A   = (const float*)d_in[9];
    const float* W_AP  = (const float*)d_in[10];
    const float* b_AP  = (const float*)d_in[11];
    const float* W_PP  = (const float*)d_in[12];
    const float* b_PP  = (const float*)d_in[13];
    const float* W_P   = (const float*)d_in[14];
    const float* b_P   = (const float*)d_in[15];

    float* outA = (float*)d_out;
    float* outP = (float*)d_out + (size_t)N_ATOMS * H;

    unsigned short* X  = (unsigned short*)d_ws;              // 100000*128*2B = 25.6MB
    float* AA          = (float*)(X + (size_t)N_ATOMS * 128);// 20MB
    float* PA          = AA + (size_t)N_ATOMS * H;           // 20MB
    int*   row_start   = (int*)(PA + (size_t)N_ATOMS * H);   // (N_ATOMS+1)*4B

    k_row_starts<<<(N_PAIRS + 255) / 256, 256, 0, stream>>>(split, row_start);
    k_atom_proj<<<N_ATOMS / 32, 256, 0, stream>>>(af, W_AA, b_AA, W_AP, b_AP, AA, X);
    k_pa_segsum<<<N_ATOMS / 4, 256, 0, stream>>>(pfeat, row_start, W_PA, b_PA, PA);
    k_atom_out<<<N_ATOMS / 32, 256, 0, stream>>>(AA, PA, W_A, b_A, outA);
    k_pair_out<<<N_PAIRS / 256, 256, 0, stream>>>(pfeat, a2p, X,
                                                  b_AP, W_PP, b_PP, W_P, b_P, outP);
}

// Round 5
// 815.261 us; speedup vs baseline: 2.2837x; 1.4273x over previous
//
#include <hip/hip_runtime.h>

#define N_ATOMS 100000
#define N_PAIRS 1600000
#define F_A 75
#define F_P 14
#define H 50

typedef float f32x2 __attribute__((ext_vector_type(2)));
typedef float f32x4 __attribute__((ext_vector_type(4)));
typedef short bf16x8 __attribute__((ext_vector_type(8)));

__device__ inline unsigned short f2bf(float f) {
    unsigned u = __float_as_uint(f);
    u += 0x7fffu + ((u >> 16) & 1u);
    return (unsigned short)(u >> 16);
}
__device__ inline float bfu(unsigned u, int hi) {
    return __uint_as_float(hi ? (u & 0xffff0000u) : (u << 16));
}

// ---------------- kernel 0: row_start[a] = lower_bound(split, a) ----------------
__global__ __launch_bounds__(256) void k_row_starts(
    const int* __restrict__ split, int* __restrict__ row_start)
{
    int p = blockIdx.x * 256 + threadIdx.x;
    if (p >= N_PAIRS) return;
    int s = split[p];
    int sp = (p == 0) ? -1 : split[p - 1];
    for (int a = sp + 1; a <= s; ++a) row_start[a] = p;
    if (p == N_PAIRS - 1)
        for (int a = s + 1; a <= N_ATOMS; ++a) row_start[a] = N_PAIRS;
}

// ---------------- kernel 1: atom projections AA (f32), X (packed bf16) ----------------
// X row = 128 bf16 (256B aligned): [0..49]=X1+b_AP, [50..63]=0, [64..113]=X2, [114..127]=0
__global__ __launch_bounds__(256) void k_atom_proj(
    const float* __restrict__ af, const float* __restrict__ W_AA,
    const float* __restrict__ b_AA, const float* __restrict__ W_AP,
    const float* __restrict__ b_AP,
    float* __restrict__ AA, unsigned short* __restrict__ X)
{
    __shared__ float sWAA[F_A * H];
    __shared__ float sWAP[2 * F_A * H];
    __shared__ float sbAA[H];
    __shared__ float sbAP[64];
    for (int t = threadIdx.x; t < F_A * H; t += 256) sWAA[t] = W_AA[t];
    for (int t = threadIdx.x; t < 2 * F_A * H; t += 256) sWAP[t] = W_AP[t];
    if (threadIdx.x < H) sbAA[threadIdx.x] = b_AA[threadIdx.x];
    if (threadIdx.x < 64) sbAP[threadIdx.x] = threadIdx.x < H ? b_AP[threadIdx.x] : 0.f;
    __syncthreads();

    const int wave = __builtin_amdgcn_readfirstlane(threadIdx.x >> 6);
    const int lane = threadIdx.x & 63;
    const int h = lane < H ? lane : 0;
    const int base = blockIdx.x * 32 + wave * 8;

    float aa[8], x1[8], x2[8];
    #pragma unroll
    for (int a = 0; a < 8; ++a) { aa[a] = sbAA[h]; x1[a] = 0.f; x2[a] = 0.f; }

    for (int c = 0; c < F_A; ++c) {
        float waa = sWAA[c * H + h];
        float w1  = sWAP[c * H + h];
        float w2  = sWAP[(F_A + c) * H + h];
        #pragma unroll
        for (int a = 0; a < 8; ++a) {
            float f = af[(base + a) * F_A + c];
            aa[a] = fmaf(f, waa, aa[a]);
            x1[a] = fmaf(f, w1, x1[a]);
            x2[a] = fmaf(f, w2, x2[a]);
        }
    }
    #pragma unroll
    for (int a = 0; a < 8; ++a) {
        int atom = base + a;
        if (lane < H) AA[(size_t)atom * H + lane] = fmaxf(aa[a], 0.f);
        unsigned short v1 = (lane < H) ? f2bf(x1[a] + sbAP[lane]) : (unsigned short)0;
        unsigned short v2 = (lane < H) ? f2bf(x2[a]) : (unsigned short)0;
        unsigned short* Xrow = X + (size_t)atom * 128;
        Xrow[lane]      = v1;
        Xrow[64 + lane] = v2;
    }
}

// ---------------- kernel 2: PA = segment_sum(relu(pf@W_PA+b)) ----------------
__global__ __launch_bounds__(256) void k_pa_segsum(
    const float* __restrict__ pf, const int* __restrict__ row_start,
    const float* __restrict__ W_PA, const float* __restrict__ b_PA,
    float* __restrict__ PA)
{
    const int wave = __builtin_amdgcn_readfirstlane(threadIdx.x >> 6);
    const int lane = threadIdx.x & 63;
    const int h = lane < H ? lane : 0;
    const int atom = blockIdx.x * 4 + wave;

    float w[F_P];
    #pragma unroll
    for (int c = 0; c < F_P; ++c) w[c] = W_PA[c * H + h];
    const float bias = b_PA[h];

    const int start = row_start[atom];
    const int end   = row_start[atom + 1];

    float acc = 0.f;
    int p = start;
    for (; p + 2 <= end; p += 2) {
        const f32x2* r0 = (const f32x2*)(pf + (size_t)p * F_P);
        const f32x2* r1 = (const f32x2*)(pf + (size_t)(p + 1) * F_P);
        float s0 = bias, s1 = bias;
        #pragma unroll
        for (int c = 0; c < 7; ++c) {
            f32x2 v0 = __builtin_nontemporal_load(r0 + c);
            f32x2 v1 = __builtin_nontemporal_load(r1 + c);
            s0 = fmaf(v0.x, w[2*c], s0); s0 = fmaf(v0.y, w[2*c+1], s0);
            s1 = fmaf(v1.x, w[2*c], s1); s1 = fmaf(v1.y, w[2*c+1], s1);
        }
        acc += fmaxf(s0, 0.f) + fmaxf(s1, 0.f);
    }
    if (p < end) {
        const f32x2* r0 = (const f32x2*)(pf + (size_t)p * F_P);
        float s0 = bias;
        #pragma unroll
        for (int c = 0; c < 7; ++c) {
            f32x2 v = __builtin_nontemporal_load(r0 + c);
            s0 = fmaf(v.x, w[2*c], s0); s0 = fmaf(v.y, w[2*c+1], s0);
        }
        acc += fmaxf(s0, 0.f);
    }
    if (lane < H) PA[(size_t)atom * H + lane] = acc;
}

// ---------------- kernel 3: A = relu([AA|PA] @ W_A + b_A) ----------------
__global__ __launch_bounds__(256) void k_atom_out(
    const float* __restrict__ AA, const float* __restrict__ PA,
    const float* __restrict__ W_A, const float* __restrict__ b_A,
    float* __restrict__ outA)
{
    __shared__ float sW[2 * H * H];
    __shared__ float sb[H];
    for (int t = threadIdx.x; t < 2 * H * H; t += 256) sW[t] = W_A[t];
    if (threadIdx.x < H) sb[threadIdx.x] = b_A[threadIdx.x];
    __syncthreads();

    const int wave = __builtin_amdgcn_readfirstlane(threadIdx.x >> 6);
    const int lane = threadIdx.x & 63;
    const int h = lane < H ? lane : 0;
    const int base = blockIdx.x * 32 + wave * 8;

    float acc[8];
    #pragma unroll
    for (int a = 0; a < 8; ++a) acc[a] = sb[h];

    for (int k = 0; k < H; ++k) {
        float wA = sW[k * H + h];
        float wP = sW[(H + k) * H + h];
        #pragma unroll
        for (int a = 0; a < 8; ++a) {
            acc[a] = fmaf(AA[(size_t)(base + a) * H + k], wA, acc[a]);
            acc[a] = fmaf(PA[(size_t)(base + a) * H + k], wP, acc[a]);
        }
    }
    #pragma unroll
    for (int a = 0; a < 8; ++a)
        if (lane < H) outA[(size_t)(base + a) * H + lane] = fmaxf(acc[a], 0.f);
}

// ---------------- kernel 4: P = relu([AP|PP] @ W_P + b_P) via MFMA ----------------
// Grid-stride over 16-pair tiles (one tile per wave). MFMA compute (validated in R3)
// + LDS-transpose epilogue with contiguous row stores (R4's store discipline).
#define PO_BLOCKS 1536
__global__ __launch_bounds__(256) void k_pair_out(
    const float* __restrict__ pf, const int* __restrict__ a2p,
    const unsigned short* __restrict__ X,
    const float* __restrict__ W_PP, const float* __restrict__ b_PP,
    const float* __restrict__ W_P, const float* __restrict__ b_P,
    float* __restrict__ outP)
{
    __shared__ uint4 sWf[1024];        // 16 B-frag sets (s=0..3, n=0..3) x 64 lanes (16KB)
    __shared__ float sWPP[F_P][64];    // 3.5KB
    __shared__ float sbPP[64];
    __shared__ float sT[4][800];       // per-wave transpose buffer [16 pairs][50], 12.5KB

    const int tid = threadIdx.x;
    // build B-frags: lane holds col=lane&15, k = s*32 + (lane>>4)*8 + [0..7]  (R3-validated)
    #pragma unroll
    for (int r = 0; r < 4; ++r) {
        int e = r * 256 + tid;
        int fid = e >> 6, lane_e = e & 63;
        int s_ = fid >> 2, n_ = fid & 3;
        int col = lane_e & 15, gg = lane_e >> 4;
        int k0 = s_ * 32 + gg * 8;
        int c = n_ * 16 + col;
        unsigned w[4];
        #pragma unroll
        for (int hh = 0; hh < 4; ++hh) {
            float vlo = 0.f, vhi = 0.f;
            if (c < H) {
                int k = k0 + 2 * hh;
                int r0 = (k < 64) ? (k < H ? k : -1) : ((k - 64) < H ? H + (k - 64) : -1);
                int k2 = k + 1;
                int r1 = (k2 < 64) ? (k2 < H ? k2 : -1) : ((k2 - 64) < H ? H + (k2 - 64) : -1);
                if (r0 >= 0) vlo = W_P[r0 * H + c];
                if (r1 >= 0) vhi = W_P[r1 * H + c];
            }
            w[hh] = (unsigned)f2bf(vlo) | ((unsigned)f2bf(vhi) << 16);
        }
        sWf[e] = make_uint4(w[0], w[1], w[2], w[3]);
    }
    for (int t = tid; t < F_P * 64; t += 256) {
        int c = t >> 6, o = t & 63;
        sWPP[c][o] = (o < H) ? W_PP[c * H + o] : 0.f;
    }
    if (tid < 64) sbPP[tid] = tid < H ? b_PP[tid] : 0.f;
    __syncthreads();

    const int lane = tid & 63;
    const int wave = tid >> 6;
    const int col = lane & 15;          // pair-local index AND output col-local
    const int g = lane >> 4;            // k-slice group
    float* const myT = sT[wave];

    float bP[4];
    #pragma unroll
    for (int n = 0; n < 4; ++n) {
        int c = n * 16 + col;
        bP[n] = (c < H) ? b_P[c] : 0.f;
    }

    const int NT = N_PAIRS / 16;        // 100000 tiles
    for (int tile = blockIdx.x * 4 + wave; tile < NT; tile += PO_BLOCKS * 4) {
        const int pairbase = tile * 16;
        const int2 ij = ((const int2*)a2p)[pairbase + col];
        const unsigned short* Xi = X + (size_t)ij.x * 128;
        const unsigned short* Xj = X + (size_t)ij.y * 128;

        // issue all 8 gathers early (each 16B, lane owns its frag chunk)
        uint4 A1[2], B2[2], B1[2], A2[2];
        #pragma unroll
        for (int s = 0; s < 2; ++s) {
            int off = s * 32 + g * 8;   // ushort offset
            A1[s] = *(const uint4*)(Xi + off);
            B2[s] = *(const uint4*)(Xj + 64 + off);
            B1[s] = *(const uint4*)(Xj + off);
            A2[s] = *(const uint4*)(Xi + 64 + off);
        }

        // pf row for PP (pair = col)
        float pfr[F_P];
        {
            const f32x2* src = (const f32x2*)(pf + (size_t)(pairbase + col) * F_P);
            #pragma unroll
            for (int c = 0; c < 7; ++c) {
                f32x2 v = __builtin_nontemporal_load(src + c);
                pfr[2*c] = v.x; pfr[2*c+1] = v.y;
            }
        }

        f32x4 acc[4];
        #pragma unroll
        for (int n = 0; n < 4; ++n) acc[n] = (f32x4){bP[n], bP[n], bP[n], bP[n]};

        // ---- PP K-steps (global k = 64..127): overlaps gather latency ----
        #pragma unroll
        for (int s2 = 0; s2 < 2; ++s2) {
            int ob = s2 * 32 + g * 8;
            float pp[8];
            {
                const f32x4* bb = (const f32x4*)&sbPP[ob];
                f32x4 b0 = bb[0], b1 = bb[1];
                pp[0]=b0.x; pp[1]=b0.y; pp[2]=b0.z; pp[3]=b0.w;
                pp[4]=b1.x; pp[5]=b1.y; pp[6]=b1.z; pp[7]=b1.w;
            }
            #pragma unroll
            for (int c = 0; c < F_P; ++c) {
                const f32x4* wr = (const f32x4*)&sWPP[c][ob];
                f32x4 w0 = wr[0], w1 = wr[1];
                float pc = pfr[c];
                pp[0]=fmaf(pc,w0.x,pp[0]); pp[1]=fmaf(pc,w0.y,pp[1]);
                pp[2]=fmaf(pc,w0.z,pp[2]); pp[3]=fmaf(pc,w0.w,pp[3]);
                pp[4]=fmaf(pc,w1.x,pp[4]); pp[5]=fmaf(pc,w1.y,pp[5]);
                pp[6]=fmaf(pc,w1.z,pp[6]); pp[7]=fmaf(pc,w1.w,pp[7]);
            }
            union { unsigned u[4]; bf16x8 v; } ap;
            #pragma unroll
            for (int hh = 0; hh < 4; ++hh) {
                float lo = fmaxf(pp[2*hh], 0.f), hi = fmaxf(pp[2*hh+1], 0.f);
                ap.u[hh] = (unsigned)f2bf(lo) | ((unsigned)f2bf(hi) << 16);
            }
            int sg = 2 + s2;
            #pragma unroll
            for (int n = 0; n < 4; ++n) {
                bf16x8 bfr = ((const bf16x8*)sWf)[(sg * 4 + n) * 64 + lane];
                acc[n] = __builtin_amdgcn_mfma_f32_16x16x32_bf16(ap.v, bfr, acc[n], 0, 0, 0);
            }
        }

        // ---- AP K-steps (global k = 0..63); b_AP pre-folded into X1 ----
        #pragma unroll
        for (int s = 0; s < 2; ++s) {
            const unsigned* a1 = (const unsigned*)&A1[s];
            const unsigned* b2 = (const unsigned*)&B2[s];
            const unsigned* b1 = (const unsigned*)&B1[s];
            const unsigned* a2 = (const unsigned*)&A2[s];
            union { unsigned u[4]; bf16x8 v; } ap;
            #pragma unroll
            for (int hh = 0; hh < 4; ++hh) {
                float e1l = bfu(a1[hh],0) + bfu(b2[hh],0);
                float e2l = bfu(b1[hh],0) + bfu(a2[hh],0);
                float apl = fmaxf(e1l, 0.f) + fmaxf(e2l, 0.f);
                float e1h = bfu(a1[hh],1) + bfu(b2[hh],1);
                float e2h = bfu(b1[hh],1) + bfu(a2[hh],1);
                float aph = fmaxf(e1h, 0.f) + fmaxf(e2h, 0.f);
                ap.u[hh] = (unsigned)f2bf(apl) | ((unsigned)f2bf(aph) << 16);
            }
            #pragma unroll
            for (int n = 0; n < 4; ++n) {
                bf16x8 bfr = ((const bf16x8*)sWf)[(s * 4 + n) * 64 + lane];
                acc[n] = __builtin_amdgcn_mfma_f32_16x16x32_bf16(ap.v, bfr, acc[n], 0, 0, 0);
            }
        }

        // ---- epilogue: transpose C frag in per-wave LDS, store contiguous rows ----
        // C frag: col = n*16+col, row(pair) = g*4+q  (R3-validated mapping)
        #pragma unroll
        for (int n = 0; n < 4; ++n) {
            int c = n * 16 + col;
            if (c < H) {
                #pragma unroll
                for (int q = 0; q < 4; ++q)
                    myT[(g * 4 + q) * H + c] = fmaxf(acc[n][q], 0.f);
            }
        }
        // 16 rows x 50 f32 = 800 floats = 3200B contiguous in outP
        float* dst = outP + (size_t)pairbase * H;
        #pragma unroll
        for (int e = 0; e < 7; ++e) {
            int idx = e * 64 + lane;           // f32x2 index, 400 total
            if (idx < 400) {
                f32x2 v = *(const f32x2*)&myT[idx * 2];
                *(f32x2*)(dst + idx * 2) = v;
            }
        }
    }
}

// ---------------- launcher ----------------
extern "C" void kernel_launch(void* const* d_in, const int* in_sizes, int n_in,
                              void* d_out, int out_size, void* d_ws, size_t ws_size,
                              hipStream_t stream) {
    const float* af    = (const float*)d_in[0];
    const float* pfeat = (const float*)d_in[1];
    const int*   split = (const int*)d_in[2];
    const int*   a2p   = (const int*)d_in[3];
    const float* W_AA  = (const float*)d_in[4];
    const float* b_AA  = (const float*)d_in[5];
    const float* W_PA  = (const float*)d_in[6];
    const float* b_PA  = (const float*)d_in[7];
    const float* W_A   = (const float*)d_in[8];
    const float* b_A   = (const float*)d_in[9];
    const float* W_AP  = (const float*)d_in[10];
    const float* b_AP  = (const float*)d_in[11];
    const float* W_PP  = (const float*)d_in[12];
    const float* b_PP  = (const float*)d_in[13];
    const float* W_P   = (const float*)d_in[14];
    const float* b_P   = (const float*)d_in[15];

    float* outA = (float*)d_out;
    float* outP = (float*)d_out + (size_t)N_ATOMS * H;

    unsigned short* X  = (unsigned short*)d_ws;              // 100000*128*2B = 25.6MB
    float* AA          = (float*)(X + (size_t)N_ATOMS * 128);// 20MB
    float* PA          = AA + (size_t)N_ATOMS * H;           // 20MB
    int*   row_start   = (int*)(PA + (size_t)N_ATOMS * H);   // (N_ATOMS+1)*4B

    k_row_starts<<<(N_PAIRS + 255) / 256, 256, 0, stream>>>(split, row_start);
    k_atom_proj<<<N_ATOMS / 32, 256, 0, stream>>>(af, W_AA, b_AA, W_AP, b_AP, AA, X);
    k_pa_segsum<<<N_ATOMS / 4, 256, 0, stream>>>(pfeat, row_start, W_PA, b_PA, PA);
    k_atom_out<<<N_ATOMS / 32, 256, 0, stream>>>(AA, PA, W_A, b_A, outA);
    k_pair_out<<<PO_BLOCKS, 256, 0, stream>>>(pfeat, a2p, X,
                                              W_PP, b_PP, W_P, b_P, outP);
}